// Round 6
// baseline (305.456 us; speedup 1.0000x reference)
//
#include <hip/hip_runtime.h>
#include <hip/hip_bf16.h>

// ViT attention, B=4 S=2048 C=1024 H=16 D=64. fp32 I/O, bf16/f16 MFMA inside.
// cast -> rope_table -> qkv_gemm(+bias+rope+scale) -> vtrans -> attn -> proj.
// R1: PV 16x16x32_f16 via permlane lq-transpose.  R3: ssum ones-MFMA +
//     zero-C + XCD remap + s_nop hazard fix.  R4/R5: GEMM dbuf + counted
//     vmcnt -> both neutral (m233: 2-phase overhead is structural).
// R6: GEMM core -> 256x128 tile, 8 waves (512 thr), per-K-tile 2-phase
//     schedule: {issue A-glds; vmcnt(4); barrier; ds_read; setprio MFMA} /
//     {issue B-glds; ds_read; MFMA; barrier}. Counted vmcnt never 0 in
//     steady state; stage split under MFMA clusters; LDS 96KB, 1 block/CU.

typedef unsigned short u16;
using bf16x8 = __attribute__((ext_vector_type(8))) __bf16;
using f32x4  = __attribute__((ext_vector_type(4))) float;
using f16x8  = __attribute__((ext_vector_type(8))) _Float16;
using fp16v2 = __attribute__((ext_vector_type(2))) __fp16;   // cvt_pkrtz native

#define LDT 80  // vtrans LDS pad only

__device__ __forceinline__ u16 f2bf(float f) {
  union { float f; unsigned u; } un; un.f = f;
  unsigned r = un.u + 0x7FFFu + ((un.u >> 16) & 1u);  // RNE
  return (u16)(r >> 16);
}
__device__ __forceinline__ float bf2f(u16 b) {
  union { unsigned u; float f; } un; un.u = ((unsigned)b) << 16;
  return un.f;
}

// pack two f32 -> two f16 (RTZ) into one dword
__device__ __forceinline__ unsigned pkrtz_u32(float a, float b) {
  union { fp16v2 v; unsigned u; } un;
  un.v = __builtin_amdgcn_cvt_pkrtz(a, b);
  return un.u;
}

// x' = [x.lo32, y.lo32]; y' = [x.hi32, y.hi32]  (gather 32-lane halves)
__device__ __forceinline__ void pswap32(unsigned &x, unsigned &y) {
  asm volatile("v_permlane32_swap_b32 %0, %1" : "+v"(x), "+v"(y));
}
// rows of 16 lanes: x' = [x0,y0,x2,y2]; y' = [x1,y1,x3,y3]
// s_nop 1 embedded: final writers of pa regs; hazard recognizer cannot see
// VALU-write->MFMA-read wait states for INLINEASM producers (R2 NaN cause).
__device__ __forceinline__ void pswap16(unsigned &x, unsigned &y) {
  asm volatile("v_permlane16_swap_b32 %0, %1\n\ts_nop 1" : "+v"(x), "+v"(y));
}

// async 16B/lane global -> LDS (lands at ldsbase + lane*16)
__device__ __forceinline__ void glds16(const void* g, void* l) {
  __builtin_amdgcn_global_load_lds(
      (__attribute__((address_space(1))) void*)(g),
      (__attribute__((address_space(3))) void*)(l), 16, 0, 0);
}

// ---------------- fp32 -> bf16 cast (vectorized x4) ------------------------
__global__ __launch_bounds__(256) void f2bf_kernel(
    const float* __restrict__ src, u16* __restrict__ dst, int n4)
{
  int i = blockIdx.x * 256 + threadIdx.x;
  if (i < n4) {
    float4 v = ((const float4*)src)[i];
    ushort4 o;
    o.x = f2bf(v.x); o.y = f2bf(v.y); o.z = f2bf(v.z); o.w = f2bf(v.w);
    ((ushort4*)dst)[i] = o;
  }
}

// ------- RoPE table: RT[m][lr] = {cos[m][lr+16j]}{sin[m][lr+16j]} bf16 -----
__global__ __launch_bounds__(256) void rope_table_kernel(
    const float* __restrict__ cs, const float* __restrict__ sn,
    u16* __restrict__ RT)
{
  int t = blockIdx.x * 256 + threadIdx.x;   // 8192*16 = 131072 exact
  int lr = t & 15, m = t >> 4;
  const float* c = cs + (size_t)m * 64;
  const float* s = sn + (size_t)m * 64;
  alignas(16) u16 o[8];
  o[0] = f2bf(c[lr]); o[1] = f2bf(c[lr + 16]);
  o[2] = f2bf(c[lr + 32]); o[3] = f2bf(c[lr + 48]);
  o[4] = f2bf(s[lr]); o[5] = f2bf(s[lr + 16]);
  o[6] = f2bf(s[lr + 32]); o[7] = f2bf(s[lr + 48]);
  *(uint4*)(RT + (size_t)t * 8) = *(const uint4*)o;
}

// ====== 256x128 BT-GEMM core, 8 waves, 2-phase/K-tile schedule ============
// Wave w (0..7): wm=(w>>1)*64 (4 M-waves), wn=(w&1)*64 (2 N-waves).
// Per-wave output 64x64 (4x4 16x16 frags) -- identical frag math to the old
// 128^2 core. XOR bank swizzle on rows of 64 u16, unchanged.

__device__ __forceinline__ void g2_stageA(
    const u16* __restrict__ A, int K, int row0, int k0, u16* AsB,
    int w, int lrow, int lcol8)
{
#pragma unroll
  for (int p = 0; p < 4; ++p) {
    int base = w * 32 + p * 8;           // 0..255 (8 waves x 32 rows)
    int rr = base + lrow;
    int cc = (lcol8 ^ (rr & 7)) << 3;
    glds16(A + (size_t)(row0 + rr) * K + k0 + cc, AsB + base * 64);
  }
}
__device__ __forceinline__ void g2_stageB(
    const u16* __restrict__ Bm, int K, int col0, int k0, u16* BsB,
    int w, int lrow, int lcol8)
{
#pragma unroll
  for (int p = 0; p < 2; ++p) {
    int base = w * 16 + p * 8;           // 0..127 (8 waves x 16 rows)
    int rr = base + lrow;
    int cc = (lcol8 ^ (rr & 7)) << 3;
    glds16(Bm + (size_t)(col0 + rr) * K + k0 + cc, BsB + base * 64);
  }
}

// one kx phase: 8 ds_read_b128 + 16 MFMA (setprio-wrapped cluster).
// Compiler inserts fine lgkmcnt between reads and dependent MFMAs.
__device__ __forceinline__ void g2_compute_kx(
    const u16* __restrict__ Asc, const u16* __restrict__ Bsc, int kx,
    int wm, int wn, int lr, int lq, f32x4 acc[4][4])
{
  bf16x8 af[4], bv[4];
  const int sl = (((kx << 2) + lq) ^ (lr & 7)) << 3;
#pragma unroll
  for (int i = 0; i < 4; ++i) {
    af[i] = *(const bf16x8*)(&Asc[(wm + i * 16 + lr) * 64 + sl]);
    bv[i] = *(const bf16x8*)(&Bsc[(wn + i * 16 + lr) * 64 + sl]);
  }
  __builtin_amdgcn_s_setprio(1);
#pragma unroll
  for (int i = 0; i < 4; ++i)
#pragma unroll
    for (int j = 0; j < 4; ++j)
      acc[i][j] = __builtin_amdgcn_mfma_f32_16x16x32_bf16(af[i], bv[j], acc[i][j], 0, 0, 0);
  __builtin_amdgcn_s_setprio(0);
}

// Per K-tile:
//  ph0: issue stageA(ks+1) ; vmcnt(4) [proves tile-ks' 6 glds landed, the 4
//       new ones fly on] ; s_barrier [cross-wave proof] ; reads+MFMA kx0
//  ph1: issue stageB(ks+1) ; reads+MFMA kx1 ; s_barrier [all reads of
//       buf(cur) retired before next tile's stageA overwrites it]
__device__ __forceinline__ void gemm_core_256x128(
    const u16* __restrict__ A, const u16* __restrict__ Bm, int K,
    int row0, int col0, u16 (*As)[256 * 64], u16 (*Bs)[128 * 64],
    f32x4 acc[4][4])
{
  const int tid = threadIdx.x;
  const int lane = tid & 63;
  const int w  = tid >> 6;              // 0..7
  const int wm = (w >> 1) << 6;
  const int wn = (w & 1) << 6;
  const int lr = lane & 15;
  const int lq = lane >> 4;
  const int lrow = lane >> 3;
  const int lcol8 = lane & 7;
  const int nk = K >> 6;

  g2_stageA(A, K, row0, 0, As[0], w, lrow, lcol8);
  g2_stageB(Bm, K, col0, 0, Bs[0], w, lrow, lcol8);

  for (int ks = 0; ks < nk; ++ks) {
    const int cur = ks & 1;
    // ---------------- phase 0 ----------------
    if (ks + 1 < nk) {
      g2_stageA(A, K, row0, (ks + 1) << 6, As[cur ^ 1], w, lrow, lcol8);
      asm volatile("s_waitcnt vmcnt(4)" ::: "memory");
    } else {
      asm volatile("s_waitcnt vmcnt(0)" ::: "memory");
    }
    __builtin_amdgcn_s_barrier();
    __builtin_amdgcn_sched_barrier(0);    // ds_reads must not hoist above
    g2_compute_kx(As[cur], Bs[cur], 0, wm, wn, lr, lq, acc);
    // ---------------- phase 1 ----------------
    if (ks + 1 < nk)
      g2_stageB(Bm, K, col0, (ks + 1) << 6, Bs[cur ^ 1], w, lrow, lcol8);
    g2_compute_kx(As[cur], Bs[cur], 1, wm, wn, lr, lq, acc);
    __builtin_amdgcn_sched_barrier(0);    // reads must not sink below
    __builtin_amdgcn_s_barrier();
  }
}

// ------- QKV projection + bias + fused RoPE (table) + scale ----------------
__global__ __launch_bounds__(512, 2) void qkv_gemm_kernel(
    const u16* __restrict__ hs, const u16* __restrict__ wq,
    const float* __restrict__ bias, const u16* __restrict__ RT,
    u16* __restrict__ Q, u16* __restrict__ K, u16* __restrict__ V)
{
  __shared__ __align__(16) u16 As[2][256 * 64];   // 64 KB
  __shared__ __align__(16) u16 Bs[2][128 * 64];   // 32 KB
  f32x4 acc[4][4];
#pragma unroll
  for (int i = 0; i < 4; ++i)
#pragma unroll
    for (int j = 0; j < 4; ++j) acc[i][j] = (f32x4){0.f, 0.f, 0.f, 0.f};

  const int row0 = blockIdx.y * 256;   // m = b*2048 + s
  const int col0 = blockIdx.x * 128;   // n in [0,3072)
  gemm_core_256x128(hs, wq, 1024, row0, col0, As, Bs, acc);

  const int lane = threadIdx.x & 63;
  const int w = threadIdx.x >> 6;
  const int lr = lane & 15, lq = lane >> 4;
  const int wm = (w >> 1) << 6, wn = (w & 1) << 6;
  const int ncol = col0 + wn;          // 64-aligned -> single (wh,h)
  const int wh = ncol >> 10;           // 0=q 1=k 2=v (wave-uniform)
  const int h  = (ncol & 1023) >> 6;
  u16* dst = (wh == 0) ? Q : ((wh == 1) ? K : V);
  const float b0 = bias[ncol + lr];
  const float b1 = bias[ncol + 16 + lr];
  const float b2 = bias[ncol + 32 + lr];
  const float b3 = bias[ncol + 48 + lr];

#pragma unroll
  for (int i = 0; i < 4; ++i)
#pragma unroll
    for (int r = 0; r < 4; ++r) {
      int m = row0 + wm + i * 16 + lq * 4 + r;   // = b*2048 + s
      float v0 = acc[i][0][r] + b0;
      float v1 = acc[i][1][r] + b1;
      float v2 = acc[i][2][r] + b2;
      float v3 = acc[i][3][r] + b3;
      int b = m >> 11, s = m & 2047;
      size_t off = ((size_t)((b << 4) + h) * 2048 + s) * 64;
      if (wh == 2) {                   // V -> f16
        union { _Float16 h2; u16 u; } c0, c1, c2, c3;
        c0.h2 = (_Float16)v0; c1.h2 = (_Float16)v1;
        c2.h2 = (_Float16)v2; c3.h2 = (_Float16)v3;
        dst[off + lr]      = c0.u;
        dst[off + 16 + lr] = c1.u;
        dst[off + 32 + lr] = c2.u;
        dst[off + 48 + lr] = c3.u;
      } else {                         // RoPE via table; Q gets 1/8*log2(e)
        alignas(16) u16 rv[8];
        *(uint4*)rv = *(const uint4*)(RT + ((size_t)m * 16 + lr) * 8);
        float o0 = v0 * bf2f(rv[0]) - v2 * bf2f(rv[4]);
        float o1 = v1 * bf2f(rv[1]) - v3 * bf2f(rv[5]);
        float o2 = v2 * bf2f(rv[2]) + v0 * bf2f(rv[6]);
        float o3 = v3 * bf2f(rv[3]) + v1 * bf2f(rv[7]);
        float sc8 = (wh == 0) ? 0.1803368801f : 1.0f;
        dst[off + lr]      = f2bf(o0 * sc8);
        dst[off + 16 + lr] = f2bf(o1 * sc8);
        dst[off + 32 + lr] = f2bf(o2 * sc8);
        dst[off + 48 + lr] = f2bf(o3 * sc8);
      }
    }
}

// ---------------- V [B,H,S,D] -> Vt [B,H,D,S] (bit-moves) ------------------
__global__ __launch_bounds__(256) void vtrans_kernel(
    const u16* __restrict__ V, u16* __restrict__ Vt)
{
  __shared__ __align__(16) u16 T[64][LDT];
  const int bh = blockIdx.y;
  const int s0 = blockIdx.x * 64;
  const u16* src = V + ((size_t)bh * 2048 + s0) * 64;
  const int r = threadIdx.x >> 2;
  const int c = (threadIdx.x & 3) << 4;
  *(uint4*)(&T[r][c])     = *(const uint4*)(src + r * 64 + c);
  *(uint4*)(&T[r][c + 8]) = *(const uint4*)(src + r * 64 + c + 8);
  __syncthreads();
  alignas(16) u16 tmp[16];
#pragma unroll
  for (int j = 0; j < 16; ++j) tmp[j] = T[c + j][r];
  u16* dst = Vt + ((size_t)bh * 64 + r) * 2048 + s0 + c;
  *(uint4*)(dst)     = *(uint4*)(&tmp[0]);
  *(uint4*)(dst + 8) = *(uint4*)(&tmp[8]);
}

// ---- attention: S^T trick, double-buffered staging, 1 barrier/iter --------
__device__ __forceinline__ void attn_stage(
    const u16* __restrict__ Kh, const u16* __restrict__ Vh, int kv0,
    u16* KsB, u16* VsB, int w, int lrow, int lcol8)
{
#pragma unroll
  for (int p = 0; p < 2; ++p) {
    int base = w * 16 + p * 8;
    int rr = base + lrow;
    int cc = (lcol8 ^ (rr & 7)) << 3;
    glds16(Kh + (size_t)(kv0 + rr) * 64 + cc, KsB + base * 64);
    glds16(Vh + (size_t)rr * 2048 + kv0 + cc, VsB + base * 64);
  }
}

__global__ __launch_bounds__(256, 4) void attn_kernel(
    const u16* __restrict__ Q, const u16* __restrict__ K,
    const u16* __restrict__ Vt, u16* __restrict__ O)
{
  __shared__ __align__(16) u16 Ks[2][64 * 64];
  __shared__ __align__(16) u16 Vs[2][64 * 64];
  // XCD-clustering remap: all 16 q-blocks of one (b,h) land on one XCD
  // (flat%8 == XCD under round-robin dispatch), so K/V hits that XCD's L2.
  const int flat = blockIdx.x + (blockIdx.y << 4);   // 0..1023
  const int xcd = flat & 7, j = flat >> 3;           // j in 0..127
  const int bh = (xcd << 3) + (j & 7);               // bijective
  const int q0 = (j >> 3) << 7;
  const int b = bh >> 4, h = bh & 15;
  const u16* Qh = Q  + (size_t)bh * (2048 * 64);
  const u16* Kh = K  + (size_t)bh * (2048 * 64);
  const u16* Vh = Vt + (size_t)bh * (64 * 2048);
  const int tid = threadIdx.x, lane = tid & 63, w = tid >> 6;
  const int lr = lane & 15, lq = lane >> 4;
  const int lrow = lane >> 3, lcol8 = lane & 7;
  const int wq0 = w * 32;

  // prefetch tile 0
  attn_stage(Kh, Vh, 0, Ks[0], Vs[0], w, lrow, lcol8);

  // Q fragments: iter-invariant, straight from global (B-operand, n=q)
  bf16x8 qa[2][2];
#pragma unroll
  for (int mi = 0; mi < 2; ++mi)
#pragma unroll
    for (int kx = 0; kx < 2; ++kx)
      qa[mi][kx] = *(const bf16x8*)(Qh + (size_t)(q0 + wq0 + mi * 16 + lr) * 64 + kx * 32 + lq * 8);

  const f32x4 Z = (f32x4){0.f, 0.f, 0.f, 0.f};   // shared zero C-in
  const f16x8 ones = {(_Float16)1.f, (_Float16)1.f, (_Float16)1.f, (_Float16)1.f,
                      (_Float16)1.f, (_Float16)1.f, (_Float16)1.f, (_Float16)1.f};

  f32x4 acc_o[2][4];
  f32x4 ssum[2];                                  // P row-sums via MFMA
#pragma unroll
  for (int mi = 0; mi < 2; ++mi) {
    ssum[mi] = (f32x4){0.f, 0.f, 0.f, 0.f};
#pragma unroll
    for (int td = 0; td < 4; ++td) acc_o[mi][td] = (f32x4){0.f, 0.f, 0.f, 0.f};
  }

  for (int it = 0; it < 32; ++it) {
    const int cur = it & 1;
    __syncthreads();                       // drains staging of buf(cur)
    if (it + 1 < 32)                       // prefetch next into other buffer
      attn_stage(Kh, Vh, (it + 1) << 6, Ks[cur ^ 1], Vs[cur ^ 1], w, lrow, lcol8);
    const u16* Kc = Ks[cur];
    const u16* Vc = Vs[cur];

    // S^T = K Q^T : tiles [kv=tj*16][q=mi*16], contraction over d
    // kx==0 uses the shared zero C-in (no per-iter acc re-zeroing)
    f32x4 st[4][2];
#pragma unroll
    for (int kx = 0; kx < 2; ++kx) {
      bf16x8 ka[4];
#pragma unroll
      for (int tj = 0; tj < 4; ++tj) {
        int row = tj * 16 + lr;
        ka[tj] = *(const bf16x8*)(&Kc[row * 64 + ((((kx << 2) + lq) ^ (lr & 7)) << 3)]);
      }
#pragma unroll
      for (int tj = 0; tj < 4; ++tj)
#pragma unroll
        for (int mi = 0; mi < 2; ++mi)
          st[tj][mi] = __builtin_amdgcn_mfma_f32_16x16x32_bf16(
              ka[tj], qa[mi][kx], kx ? st[tj][mi] : Z, 0, 0, 0);
    }

    // p = 2^s (log2e pre-folded into Q). Build K=32 f16 A-frags:
    // S^T C-layout gives lane (lq,lr): P[q=lr][kv = tj*16 + lq*4 + r].
    // K=32 A-layout needs lane to hold kv = lq*8+i, i=0..7 -- a 4x4
    // lq-transpose done with 2x permlane32_swap + 2x permlane16_swap.
    f16x8 pa[2][2];
#pragma unroll
    for (int mi = 0; mi < 2; ++mi)
#pragma unroll
      for (int t32 = 0; t32 < 2; ++t32) {
        unsigned dw[4];
#pragma unroll
        for (int tt = 0; tt < 2; ++tt) {
          const int tj = t32 * 2 + tt;
          float e0 = __builtin_amdgcn_exp2f(st[tj][mi][0]);
          float e1 = __builtin_amdgcn_exp2f(st[tj][mi][1]);
          float e2 = __builtin_amdgcn_exp2f(st[tj][mi][2]);
          float e3 = __builtin_amdgcn_exp2f(st[tj][mi][3]);
          dw[tt * 2 + 0] = pkrtz_u32(e0, e1);   // kv_local lq*4+{0,1}
          dw[tt * 2 + 1] = pkrtz_u32(e2, e3);   // kv_local lq*4+{2,3}
        }
        pswap32(dw[0], dw[2]);
        pswap32(dw[1], dw[3]);
        pswap16(dw[0], dw[2]);
        pswap16(dw[1], dw[3]);
        union { unsigned u[4]; f16x8 v; } P;
        P.u[0] = dw[0]; P.u[1] = dw[1]; P.u[2] = dw[2]; P.u[3] = dw[3];
        pa[mi][t32] = P.v;
      }

    // O += P V  (full-rate K=32 f16 MFMA); row-sums ride the matrix pipe
    // AFTER the PV MFMAs (schedule distance from the permlane writes):
    // mfma(pa, ones) -> C[q][*] = sum_kv P, landing at row=lq*4+r exactly
    // where the epilogue needs it (no cross-lane reduce).
#pragma unroll
    for (int t32 = 0; t32 < 2; ++t32) {
      f16x8 bv[4];
#pragma unroll
      for (int td = 0; td < 4; ++td) {
        int row = td * 16 + lr;
        bv[td] = *(const f16x8*)(&Vc[row * 64 + ((((t32 << 2) + lq) ^ (lr & 7)) << 3)]);
      }
#pragma unroll
      for (int td = 0; td < 4; ++td)
#pragma unroll
        for (int mi = 0; mi < 2; ++mi)
          acc_o[mi][td] = __builtin_amdgcn_mfma_f32_16x16x32_f16(pa[mi][t32], bv[td], acc_o[mi][td], 0, 0, 0);
#pragma unroll
      for (int mi = 0; mi < 2; ++mi)
        ssum[mi] = __builtin_amdgcn_mfma_f32_16x16x32_f16(pa[mi][t32], ones, ssum[mi], 0, 0, 0);
    }
  }

  // ssum[mi][r] holds the denom for q-row lq*4+r (all lr identical)
#pragma unroll
  for (int mi = 0; mi < 2; ++mi)
#pragma unroll
    for (int r = 0; r < 4; ++r) {
      float inv = 1.f / ssum[mi][r];
      int qq = q0 + wq0 + mi * 16 + lq * 4 + r;
#pragma unroll
      for (int td = 0; td < 4; ++td) {
        int d = td * 16 + lr;
        O[(size_t)(b * 2048 + qq) * 1024 + h * 64 + d] = f2bf(acc_o[mi][td][r] * inv);
      }
    }
}

// ---------------- output projection (fp32 out) -----------------------------
__global__ __launch_bounds__(512, 2) void proj_gemm_kernel(
    const u16* __restrict__ X, const u16* __restrict__ wp,
    const float* __restrict__ bias, float* __restrict__ out)
{
  __shared__ __align__(16) u16 As[2][256 * 64];
  __shared__ __align__(16) u16 Bs[2][128 * 64];
  f32x4 acc[4][4];
#pragma unroll
  for (int i = 0; i < 4; ++i)
#pragma unroll
    for (int j = 0; j < 4; ++j) acc[i][j] = (f32x4){0.f, 0.f, 0.f, 0.f};

  const int row0 = blockIdx.y * 256;
  const int col0 = blockIdx.x * 128;
  gemm_core_256x128(X, wp, 1024, row0, col0, As, Bs, acc);

  const int lane = threadIdx.x & 63;
  const int w = threadIdx.x >> 6;
  const int wm = (w >> 1) << 6, wn = (w & 1) << 6;
#pragma unroll
  for (int i = 0; i < 4; ++i)
#pragma unroll
    for (int j = 0; j < 4; ++j)
#pragma unroll
      for (int r = 0; r < 4; ++r) {
        int m = row0 + wm + i * 16 + ((lane >> 4) << 2) + r;
        int n = col0 + wn + j * 16 + (lane & 15);
        out[(size_t)m * 1024 + n] = acc[i][j][r] + bias[n];
      }
}

extern "C" void kernel_launch(void* const* d_in, const int* in_sizes, int n_in,
                              void* d_out, int out_size, void* d_ws, size_t ws_size,
                              hipStream_t stream)
{
  const float* hs   = (const float*)d_in[0];
  const float* cs   = (const float*)d_in[1];
  const float* sn   = (const float*)d_in[2];
  const float* qkvw = (const float*)d_in[3];
  const float* qkvb = (const float*)d_in[4];
  const float* pw   = (const float*)d_in[5];
  const float* pb   = (const float*)d_in[6];
  float* out = (float*)d_out;

  const size_t NQ = (size_t)8192 * 1024;
  u16* hsb   = (u16*)d_ws;
  u16* qkvwb = hsb + NQ;
  u16* pwb   = qkvwb + 3145728;
  u16* Qb    = pwb + 1048576;
  u16* Kb    = Qb + NQ;
  u16* Vb    = Kb + NQ;      // f16
  u16* Vtb   = Vb + NQ;      // f16
  u16* RT    = Vtb + NQ;     // rope table, 8192*16*8 u16 = 2 MB
  u16* Ob    = hsb;          // alias: hs consumed after qkv

  f2bf_kernel<<<8192, 256, 0, stream>>>(hs, hsb, (int)(NQ / 4));
  f2bf_kernel<<<3072, 256, 0, stream>>>(qkvw, qkvwb, 3145728 / 4);
  f2bf_kernel<<<1024, 256, 0, stream>>>(pw, pwb, 1048576 / 4);
  rope_table_kernel<<<512, 256, 0, stream>>>(cs, sn, RT);

  qkv_gemm_kernel<<<dim3(24, 32), 512, 0, stream>>>(hsb, qkvwb, qkvb, RT, Qb, Kb, Vb);
  vtrans_kernel<<<dim3(32, 64), 256, 0, stream>>>(Vb, Vtb);
  attn_kernel<<<dim3(16, 64), 256, 0, stream>>>(Qb, Kb, Vtb, Ob);
  proj_gemm_kernel<<<dim3(8, 32), 512, 0, stream>>>(Ob, pwb, pb, out);
}

// Round 7
// 287.081 us; speedup vs baseline: 1.0640x; 1.0640x over previous
//
#include <hip/hip_runtime.h>
#include <hip/hip_bf16.h>

// ViT attention, B=4 S=2048 C=1024 H=16 D=64. fp32 I/O, bf16/f16 MFMA inside.
// cast -> rope_table -> qkv_gemm(+bias+rope+scale) -> vtrans -> attn -> proj.
// R1: PV 16x16x32_f16 via permlane lq-transpose.  R3: ssum ones-MFMA +
//     zero-C + XCD remap (attn) + s_nop hazard fix.  R4/R5/R6: three GEMM
//     schedule reworks all neutral; MfmaUtil pinned at ~23% -> stall is NOT
//     schedule-local.
// R7: locality theory: default dispatch puts each A row-panel on ALL 8 XCDs
//     (active A/XCD ~10.7MB >> 4MB L2 -> thrash; FETCH 87MB vs 23MB unique).
//     XCD-aware remap: each XCD runs complete row-panel runs (24 col-blocks
//     consecutively), panels striped xcd+8k -> active A/XCD ~1.4MB. Core
//     reverted to R5 128^2 counted-vmcnt (known-equal).

typedef unsigned short u16;
using bf16x8 = __attribute__((ext_vector_type(8))) __bf16;
using f32x4  = __attribute__((ext_vector_type(4))) float;
using f16x8  = __attribute__((ext_vector_type(8))) _Float16;
using fp16v2 = __attribute__((ext_vector_type(2))) __fp16;   // cvt_pkrtz native

#define LDT 80  // vtrans LDS pad only

__device__ __forceinline__ u16 f2bf(float f) {
  union { float f; unsigned u; } un; un.f = f;
  unsigned r = un.u + 0x7FFFu + ((un.u >> 16) & 1u);  // RNE
  return (u16)(r >> 16);
}
__device__ __forceinline__ float bf2f(u16 b) {
  union { unsigned u; float f; } un; un.u = ((unsigned)b) << 16;
  return un.f;
}

// pack two f32 -> two f16 (RTZ) into one dword
__device__ __forceinline__ unsigned pkrtz_u32(float a, float b) {
  union { fp16v2 v; unsigned u; } un;
  un.v = __builtin_amdgcn_cvt_pkrtz(a, b);
  return un.u;
}

// x' = [x.lo32, y.lo32]; y' = [x.hi32, y.hi32]  (gather 32-lane halves)
__device__ __forceinline__ void pswap32(unsigned &x, unsigned &y) {
  asm volatile("v_permlane32_swap_b32 %0, %1" : "+v"(x), "+v"(y));
}
// rows of 16 lanes: x' = [x0,y0,x2,y2]; y' = [x1,y1,x3,y3]
// s_nop 1 embedded: final writers of pa regs; hazard recognizer cannot see
// VALU-write->MFMA-read wait states for INLINEASM producers (R2 NaN cause).
__device__ __forceinline__ void pswap16(unsigned &x, unsigned &y) {
  asm volatile("v_permlane16_swap_b32 %0, %1\n\ts_nop 1" : "+v"(x), "+v"(y));
}

// async 16B/lane global -> LDS (lands at ldsbase + lane*16)
__device__ __forceinline__ void glds16(const void* g, void* l) {
  __builtin_amdgcn_global_load_lds(
      (__attribute__((address_space(1))) void*)(g),
      (__attribute__((address_space(3))) void*)(l), 16, 0, 0);
}

// ---------------- fp32 -> bf16 cast (vectorized x4) ------------------------
__global__ __launch_bounds__(256) void f2bf_kernel(
    const float* __restrict__ src, u16* __restrict__ dst, int n4)
{
  int i = blockIdx.x * 256 + threadIdx.x;
  if (i < n4) {
    float4 v = ((const float4*)src)[i];
    ushort4 o;
    o.x = f2bf(v.x); o.y = f2bf(v.y); o.z = f2bf(v.z); o.w = f2bf(v.w);
    ((ushort4*)dst)[i] = o;
  }
}

// ------- RoPE table: RT[m][lr] = {cos[m][lr+16j]}{sin[m][lr+16j]} bf16 -----
__global__ __launch_bounds__(256) void rope_table_kernel(
    const float* __restrict__ cs, const float* __restrict__ sn,
    u16* __restrict__ RT)
{
  int t = blockIdx.x * 256 + threadIdx.x;   // 8192*16 = 131072 exact
  int lr = t & 15, m = t >> 4;
  const float* c = cs + (size_t)m * 64;
  const float* s = sn + (size_t)m * 64;
  alignas(16) u16 o[8];
  o[0] = f2bf(c[lr]); o[1] = f2bf(c[lr + 16]);
  o[2] = f2bf(c[lr + 32]); o[3] = f2bf(c[lr + 48]);
  o[4] = f2bf(s[lr]); o[5] = f2bf(s[lr + 16]);
  o[6] = f2bf(s[lr + 32]); o[7] = f2bf(s[lr + 48]);
  *(uint4*)(RT + (size_t)t * 8) = *(const uint4*)o;
}

// ------ 128x128 BT-GEMM core, counted-vmcnt dbuf + XOR bank swizzle --------
__device__ __forceinline__ void gemm_stage_128(
    const u16* __restrict__ A, const u16* __restrict__ Bm, int K,
    int row0, int col0, int k0, u16* AsB, u16* BsB,
    int w, int lrow, int lcol8)
{
#pragma unroll
  for (int p = 0; p < 4; ++p) {
    int base = w * 32 + p * 8;
    int rr = base + lrow;
    int cc = (lcol8 ^ (rr & 7)) << 3;
    glds16(A  + (size_t)(row0 + rr) * K + k0 + cc, AsB + base * 64);
    glds16(Bm + (size_t)(col0 + rr) * K + k0 + cc, BsB + base * 64);
  }
}

__device__ __forceinline__ void gemm_compute_128(
    const u16* __restrict__ Asc, const u16* __restrict__ Bsc,
    int wm, int wn, int lr, int lq, f32x4 acc[4][4])
{
#pragma unroll
  for (int kx = 0; kx < 2; ++kx) {
    bf16x8 af[4], bv[4];
    const int sl = (((kx << 2) + lq) ^ (lr & 7)) << 3;
#pragma unroll
    for (int i = 0; i < 4; ++i) {
      af[i] = *(const bf16x8*)(&Asc[(wm + i * 16 + lr) * 64 + sl]);
      bv[i] = *(const bf16x8*)(&Bsc[(wn + i * 16 + lr) * 64 + sl]);
    }
#pragma unroll
    for (int i = 0; i < 4; ++i)
#pragma unroll
      for (int j = 0; j < 4; ++j)
        acc[i][j] = __builtin_amdgcn_mfma_f32_16x16x32_bf16(af[i], bv[j], acc[i][j], 0, 0, 0);
  }
}

// Counted-vmcnt double-buffered K-loop (R5, perf-equal to all variants).
__device__ __forceinline__ void gemm_core_128(
    const u16* __restrict__ A, const u16* __restrict__ Bm, int K,
    int row0, int col0, u16 (*As)[128 * 64], u16 (*Bs)[128 * 64],
    f32x4 acc[4][4])
{
  const int tid = threadIdx.x;
  const int lane = tid & 63;
  const int w  = tid >> 6;
  const int wm = (w >> 1) << 6;
  const int wn = (w & 1) << 6;
  const int lr = lane & 15;
  const int lq = lane >> 4;
  const int lrow = lane >> 3;
  const int lcol8 = lane & 7;
  const int nk = K >> 6;

  gemm_stage_128(A, Bm, K, row0, col0, 0, As[0], Bs[0], w, lrow, lcol8);

  for (int ks = 0; ks < nk - 1; ++ks) {
    const int cur = ks & 1;
    gemm_stage_128(A, Bm, K, row0, col0, (ks + 1) << 6,
                   As[cur ^ 1], Bs[cur ^ 1], w, lrow, lcol8);
    asm volatile("s_waitcnt vmcnt(8)" ::: "memory");  // 8 newest may fly on
    __builtin_amdgcn_s_barrier();
    __builtin_amdgcn_sched_barrier(0);   // no ds_read hoists above barrier
    gemm_compute_128(As[cur], Bs[cur], wm, wn, lr, lq, acc);
    __builtin_amdgcn_sched_barrier(0);   // no compute sinks below barrier
    __builtin_amdgcn_s_barrier();
  }
  asm volatile("s_waitcnt vmcnt(0)" ::: "memory");    // last tile: full drain
  __builtin_amdgcn_s_barrier();
  __builtin_amdgcn_sched_barrier(0);
  gemm_compute_128(As[(nk - 1) & 1], Bs[(nk - 1) & 1], wm, wn, lr, lq, acc);
}

// ------- QKV projection + bias + fused RoPE (table) + scale ----------------
__global__ __launch_bounds__(256) void qkv_gemm_kernel(
    const u16* __restrict__ hs, const u16* __restrict__ wq,
    const float* __restrict__ bias, const u16* __restrict__ RT,
    u16* __restrict__ Q, u16* __restrict__ K, u16* __restrict__ V)
{
  __shared__ __align__(16) u16 As[2][128 * 64];
  __shared__ __align__(16) u16 Bs[2][128 * 64];
  f32x4 acc[4][4];
#pragma unroll
  for (int i = 0; i < 4; ++i)
#pragma unroll
    for (int j = 0; j < 4; ++j) acc[i][j] = (f32x4){0.f, 0.f, 0.f, 0.f};

  // XCD locality remap: HW round-robins dispatch id over 8 XCDs. Give each
  // XCD complete row-panel runs (24 consecutive col-blocks of one A-panel),
  // panels striped xcd + 8k: active A per XCD ~1.4MB (fits 4MB L2) instead
  // of ~10.7MB (thrash). Bijective: (xcd,j) with j=jq*24+jc, jq<8, jc<24.
  const int flat = blockIdx.x + blockIdx.y * 24;   // 0..1535, x fastest
  const int xcd = flat & 7, j = flat >> 3;         // j in 0..191
  const int row0 = (xcd + ((j / 24) << 3)) << 7;   // m-panel = xcd + 8*(j/24)
  const int col0 = (j % 24) << 7;                  // n in [0,3072)
  gemm_core_128(hs, wq, 1024, row0, col0, As, Bs, acc);

  const int lane = threadIdx.x & 63;
  const int w = threadIdx.x >> 6;
  const int lr = lane & 15, lq = lane >> 4;
  const int wm = (w >> 1) << 6, wn = (w & 1) << 6;
  const int ncol = col0 + wn;          // 64-aligned -> single (wh,h)
  const int wh = ncol >> 10;           // 0=q 1=k 2=v (wave-uniform)
  const int h  = (ncol & 1023) >> 6;
  u16* dst = (wh == 0) ? Q : ((wh == 1) ? K : V);
  const float b0 = bias[ncol + lr];
  const float b1 = bias[ncol + 16 + lr];
  const float b2 = bias[ncol + 32 + lr];
  const float b3 = bias[ncol + 48 + lr];

#pragma unroll
  for (int i = 0; i < 4; ++i)
#pragma unroll
    for (int r = 0; r < 4; ++r) {
      int m = row0 + wm + i * 16 + lq * 4 + r;   // = b*2048 + s
      float v0 = acc[i][0][r] + b0;
      float v1 = acc[i][1][r] + b1;
      float v2 = acc[i][2][r] + b2;
      float v3 = acc[i][3][r] + b3;
      int b = m >> 11, s = m & 2047;
      size_t off = ((size_t)((b << 4) + h) * 2048 + s) * 64;
      if (wh == 2) {                   // V -> f16
        union { _Float16 h2; u16 u; } c0, c1, c2, c3;
        c0.h2 = (_Float16)v0; c1.h2 = (_Float16)v1;
        c2.h2 = (_Float16)v2; c3.h2 = (_Float16)v3;
        dst[off + lr]      = c0.u;
        dst[off + 16 + lr] = c1.u;
        dst[off + 32 + lr] = c2.u;
        dst[off + 48 + lr] = c3.u;
      } else {                         // RoPE via table; Q gets 1/8*log2(e)
        alignas(16) u16 rv[8];
        *(uint4*)rv = *(const uint4*)(RT + ((size_t)m * 16 + lr) * 8);
        float o0 = v0 * bf2f(rv[0]) - v2 * bf2f(rv[4]);
        float o1 = v1 * bf2f(rv[1]) - v3 * bf2f(rv[5]);
        float o2 = v2 * bf2f(rv[2]) + v0 * bf2f(rv[6]);
        float o3 = v3 * bf2f(rv[3]) + v1 * bf2f(rv[7]);
        float sc8 = (wh == 0) ? 0.1803368801f : 1.0f;
        dst[off + lr]      = f2bf(o0 * sc8);
        dst[off + 16 + lr] = f2bf(o1 * sc8);
        dst[off + 32 + lr] = f2bf(o2 * sc8);
        dst[off + 48 + lr] = f2bf(o3 * sc8);
      }
    }
}

// ---------------- V [B,H,S,D] -> Vt [B,H,D,S] (bit-moves) ------------------
__global__ __launch_bounds__(256) void vtrans_kernel(
    const u16* __restrict__ V, u16* __restrict__ Vt)
{
  __shared__ __align__(16) u16 T[64][LDT];
  const int bh = blockIdx.y;
  const int s0 = blockIdx.x * 64;
  const u16* src = V + ((size_t)bh * 2048 + s0) * 64;
  const int r = threadIdx.x >> 2;
  const int c = (threadIdx.x & 3) << 4;
  *(uint4*)(&T[r][c])     = *(const uint4*)(src + r * 64 + c);
  *(uint4*)(&T[r][c + 8]) = *(const uint4*)(src + r * 64 + c + 8);
  __syncthreads();
  alignas(16) u16 tmp[16];
#pragma unroll
  for (int j = 0; j < 16; ++j) tmp[j] = T[c + j][r];
  u16* dst = Vt + ((size_t)bh * 64 + r) * 2048 + s0 + c;
  *(uint4*)(dst)     = *(uint4*)(&tmp[0]);
  *(uint4*)(dst + 8) = *(uint4*)(&tmp[8]);
}

// ---- attention: S^T trick, double-buffered staging, 1 barrier/iter --------
__device__ __forceinline__ void attn_stage(
    const u16* __restrict__ Kh, const u16* __restrict__ Vh, int kv0,
    u16* KsB, u16* VsB, int w, int lrow, int lcol8)
{
#pragma unroll
  for (int p = 0; p < 2; ++p) {
    int base = w * 16 + p * 8;
    int rr = base + lrow;
    int cc = (lcol8 ^ (rr & 7)) << 3;
    glds16(Kh + (size_t)(kv0 + rr) * 64 + cc, KsB + base * 64);
    glds16(Vh + (size_t)rr * 2048 + kv0 + cc, VsB + base * 64);
  }
}

__global__ __launch_bounds__(256, 4) void attn_kernel(
    const u16* __restrict__ Q, const u16* __restrict__ K,
    const u16* __restrict__ Vt, u16* __restrict__ O)
{
  __shared__ __align__(16) u16 Ks[2][64 * 64];
  __shared__ __align__(16) u16 Vs[2][64 * 64];
  // XCD-clustering remap: all 16 q-blocks of one (b,h) land on one XCD
  // (flat%8 == XCD under round-robin dispatch), so K/V hits that XCD's L2.
  const int flat = blockIdx.x + (blockIdx.y << 4);   // 0..1023
  const int xcd = flat & 7, j = flat >> 3;           // j in 0..127
  const int bh = (xcd << 3) + (j & 7);               // bijective
  const int q0 = (j >> 3) << 7;
  const int b = bh >> 4, h = bh & 15;
  const u16* Qh = Q  + (size_t)bh * (2048 * 64);
  const u16* Kh = K  + (size_t)bh * (2048 * 64);
  const u16* Vh = Vt + (size_t)bh * (64 * 2048);
  const int tid = threadIdx.x, lane = tid & 63, w = tid >> 6;
  const int lr = lane & 15, lq = lane >> 4;
  const int lrow = lane >> 3, lcol8 = lane & 7;
  const int wq0 = w * 32;

  // prefetch tile 0
  attn_stage(Kh, Vh, 0, Ks[0], Vs[0], w, lrow, lcol8);

  // Q fragments: iter-invariant, straight from global (B-operand, n=q)
  bf16x8 qa[2][2];
#pragma unroll
  for (int mi = 0; mi < 2; ++mi)
#pragma unroll
    for (int kx = 0; kx < 2; ++kx)
      qa[mi][kx] = *(const bf16x8*)(Qh + (size_t)(q0 + wq0 + mi * 16 + lr) * 64 + kx * 32 + lq * 8);

  const f32x4 Z = (f32x4){0.f, 0.f, 0.f, 0.f};   // shared zero C-in
  const f16x8 ones = {(_Float16)1.f, (_Float16)1.f, (_Float16)1.f, (_Float16)1.f,
                      (_Float16)1.f, (_Float16)1.f, (_Float16)1.f, (_Float16)1.f};

  f32x4 acc_o[2][4];
  f32x4 ssum[2];                                  // P row-sums via MFMA
#pragma unroll
  for (int mi = 0; mi < 2; ++mi) {
    ssum[mi] = (f32x4){0.f, 0.f, 0.f, 0.f};
#pragma unroll
    for (int td = 0; td < 4; ++td) acc_o[mi][td] = (f32x4){0.f, 0.f, 0.f, 0.f};
  }

  for (int it = 0; it < 32; ++it) {
    const int cur = it & 1;
    __syncthreads();                       // drains staging of buf(cur)
    if (it + 1 < 32)                       // prefetch next into other buffer
      attn_stage(Kh, Vh, (it + 1) << 6, Ks[cur ^ 1], Vs[cur ^ 1], w, lrow, lcol8);
    const u16* Kc = Ks[cur];
    const u16* Vc = Vs[cur];

    // S^T = K Q^T : tiles [kv=tj*16][q=mi*16], contraction over d
    // kx==0 uses the shared zero C-in (no per-iter acc re-zeroing)
    f32x4 st[4][2];
#pragma unroll
    for (int kx = 0; kx < 2; ++kx) {
      bf16x8 ka[4];
#pragma unroll
      for (int tj = 0; tj < 4; ++tj) {
        int row = tj * 16 + lr;
        ka[tj] = *(const bf16x8*)(&Kc[row * 64 + ((((kx << 2) + lq) ^ (lr & 7)) << 3)]);
      }
#pragma unroll
      for (int tj = 0; tj < 4; ++tj)
#pragma unroll
        for (int mi = 0; mi < 2; ++mi)
          st[tj][mi] = __builtin_amdgcn_mfma_f32_16x16x32_bf16(
              ka[tj], qa[mi][kx], kx ? st[tj][mi] : Z, 0, 0, 0);
    }

    // p = 2^s (log2e pre-folded into Q). Build K=32 f16 A-frags:
    // S^T C-layout gives lane (lq,lr): P[q=lr][kv = tj*16 + lq*4 + r].
    // K=32 A-layout needs lane to hold kv = lq*8+i, i=0..7 -- a 4x4
    // lq-transpose done with 2x permlane32_swap + 2x permlane16_swap.
    f16x8 pa[2][2];
#pragma unroll
    for (int mi = 0; mi < 2; ++mi)
#pragma unroll
      for (int t32 = 0; t32 < 2; ++t32) {
        unsigned dw[4];
#pragma unroll
        for (int tt = 0; tt < 2; ++tt) {
          const int tj = t32 * 2 + tt;
          float e0 = __builtin_amdgcn_exp2f(st[tj][mi][0]);
          float e1 = __builtin_amdgcn_exp2f(st[tj][mi][1]);
          float e2 = __builtin_amdgcn_exp2f(st[tj][mi][2]);
          float e3 = __builtin_amdgcn_exp2f(st[tj][mi][3]);
          dw[tt * 2 + 0] = pkrtz_u32(e0, e1);   // kv_local lq*4+{0,1}
          dw[tt * 2 + 1] = pkrtz_u32(e2, e3);   // kv_local lq*4+{2,3}
        }
        pswap32(dw[0], dw[2]);
        pswap32(dw[1], dw[3]);
        pswap16(dw[0], dw[2]);
        pswap16(dw[1], dw[3]);
        union { unsigned u[4]; f16x8 v; } P;
        P.u[0] = dw[0]; P.u[1] = dw[1]; P.u[2] = dw[2]; P.u[3] = dw[3];
        pa[mi][t32] = P.v;
      }

    // O += P V  (full-rate K=32 f16 MFMA); row-sums ride the matrix pipe
    // AFTER the PV MFMAs (schedule distance from the permlane writes):
    // mfma(pa, ones) -> C[q][*] = sum_kv P, landing at row=lq*4+r exactly
    // where the epilogue needs it (no cross-lane reduce).
#pragma unroll
    for (int t32 = 0; t32 < 2; ++t32) {
      f16x8 bv[4];
#pragma unroll
      for (int td = 0; td < 4; ++td) {
        int row = td * 16 + lr;
        bv[td] = *(const f16x8*)(&Vc[row * 64 + ((((t32 << 2) + lq) ^ (lr & 7)) << 3)]);
      }
#pragma unroll
      for (int td = 0; td < 4; ++td)
#pragma unroll
        for (int mi = 0; mi < 2; ++mi)
          acc_o[mi][td] = __builtin_amdgcn_mfma_f32_16x16x32_f16(pa[mi][t32], bv[td], acc_o[mi][td], 0, 0, 0);
#pragma unroll
      for (int mi = 0; mi < 2; ++mi)
        ssum[mi] = __builtin_amdgcn_mfma_f32_16x16x32_f16(pa[mi][t32], ones, ssum[mi], 0, 0, 0);
    }
  }

  // ssum[mi][r] holds the denom for q-row lq*4+r (all lr identical)
#pragma unroll
  for (int mi = 0; mi < 2; ++mi)
#pragma unroll
    for (int r = 0; r < 4; ++r) {
      float inv = 1.f / ssum[mi][r];
      int qq = q0 + wq0 + mi * 16 + lq * 4 + r;
#pragma unroll
      for (int td = 0; td < 4; ++td) {
        int d = td * 16 + lr;
        O[(size_t)(b * 2048 + qq) * 1024 + h * 64 + d] = f2bf(acc_o[mi][td][r] * inv);
      }
    }
}

// ---------------- output projection (fp32 out) -----------------------------
__global__ __launch_bounds__(256) void proj_gemm_kernel(
    const u16* __restrict__ X, const u16* __restrict__ wp,
    const float* __restrict__ bias, float* __restrict__ out)
{
  __shared__ __align__(16) u16 As[2][128 * 64];
  __shared__ __align__(16) u16 Bs[2][128 * 64];
  f32x4 acc[4][4];
#pragma unroll
  for (int i = 0; i < 4; ++i)
#pragma unroll
    for (int j = 0; j < 4; ++j) acc[i][j] = (f32x4){0.f, 0.f, 0.f, 0.f};

  // Same XCD locality remap (8 col-blocks per row-panel here).
  const int flat = blockIdx.x + (blockIdx.y << 3);   // 0..511, x fastest
  const int xcd = flat & 7, j = flat >> 3;           // j in 0..63
  const int row0 = (xcd + (j & ~7)) << 7;            // m-panel = xcd + 8*(j/8)
  const int col0 = (j & 7) << 7;
  gemm_core_128(X, wp, 1024, row0, col0, As, Bs, acc);

  const int lane = threadIdx.x & 63;
  const int w = threadIdx.x >> 6;
  const int wm = (w >> 1) << 6, wn = (w & 1) << 6;
#pragma unroll
  for (int i = 0; i < 4; ++i)
#pragma unroll
    for (int j2 = 0; j2 < 4; ++j2)
#pragma unroll
      for (int r = 0; r < 4; ++r) {
        int m = row0 + wm + i * 16 + ((lane >> 4) << 2) + r;
        int n = col0 + wn + j2 * 16 + (lane & 15);
        out[(size_t)m * 1024 + n] = acc[i][j2][r] + bias[n];
      }
}

extern "C" void kernel_launch(void* const* d_in, const int* in_sizes, int n_in,
                              void* d_out, int out_size, void* d_ws, size_t ws_size,
                              hipStream_t stream)
{
  const float* hs   = (const float*)d_in[0];
  const float* cs   = (const float*)d_in[1];
  const float* sn   = (const float*)d_in[2];
  const float* qkvw = (const float*)d_in[3];
  const float* qkvb = (const float*)d_in[4];
  const float* pw   = (const float*)d_in[5];
  const float* pb   = (const float*)d_in[6];
  float* out = (float*)d_out;

  const size_t NQ = (size_t)8192 * 1024;
  u16* hsb   = (u16*)d_ws;
  u16* qkvwb = hsb + NQ;
  u16* pwb   = qkvwb + 3145728;
  u16* Qb    = pwb + 1048576;
  u16* Kb    = Qb + NQ;
  u16* Vb    = Kb + NQ;      // f16
  u16* Vtb   = Vb + NQ;      // f16
  u16* RT    = Vtb + NQ;     // rope table, 8192*16*8 u16 = 2 MB
  u16* Ob    = hsb;          // alias: hs consumed after qkv

  f2bf_kernel<<<8192, 256, 0, stream>>>(hs, hsb, (int)(NQ / 4));
  f2bf_kernel<<<3072, 256, 0, stream>>>(qkvw, qkvwb, 3145728 / 4);
  f2bf_kernel<<<1024, 256, 0, stream>>>(pw, pwb, 1048576 / 4);
  rope_table_kernel<<<512, 256, 0, stream>>>(cs, sn, RT);

  qkv_gemm_kernel<<<dim3(24, 64), 256, 0, stream>>>(hsb, qkvwb, qkvb, RT, Qb, Kb, Vb);
  vtrans_kernel<<<dim3(32, 64), 256, 0, stream>>>(Vb, Vtb);
  attn_kernel<<<dim3(16, 64), 256, 0, stream>>>(Qb, Kb, Vtb, Ob);
  proj_gemm_kernel<<<dim3(8, 64), 256, 0, stream>>>(Ob, pwb, pb, out);
}